// Round 19
// baseline (248.047 us; speedup 1.0000x reference)
//
#include <hip/hip_runtime.h>
#include <cstddef>
#include <cstdint>

#define NN 20000
#define NE 640000
#define MP 20096       // padded rows (314*64)
#define KA 224         // A row length (halfs)
#define NC 16
#define CHUNK 40000    // NE / NC
#define NB_SCAN 79     // ceil(NN/256)
#define NB_HIST 2500   // (NE+255)/256

typedef _Float16 f16x8 __attribute__((ext_vector_type(8)));
typedef float f32x4 __attribute__((ext_vector_type(4)));
typedef unsigned short u16x8 __attribute__((ext_vector_type(8)));
typedef unsigned short u16x4 __attribute__((ext_vector_type(4)));

__device__ __forceinline__ float h2f(unsigned short u) {
    _Float16 h;
    *reinterpret_cast<unsigned short*>(&h) = u;
    return (float)h;
}
__device__ __forceinline__ unsigned short f2h(float f) {
    _Float16 h = (_Float16)f;
    return *reinterpret_cast<unsigned short*>(&h);
}
// fp16 two-term split: x ~= hi + lo (22 effective mantissa bits)
__device__ __forceinline__ void splitf(float x, unsigned short& hi, unsigned short& lo) {
    _Float16 h = (_Float16)x;
    _Float16 l = (_Float16)(x - (float)h);
    hi = *reinterpret_cast<unsigned short*>(&h);
    lo = *reinterpret_cast<unsigned short*>(&l);
}

// ---------------- setup ----------------
// ONE prep kernel:
//   blocks [0,5000):     zero cnt (+gcounter,done) + build fp16 h table
//   blocks [5000,5018):  fold main (t, k0-chunk) -> B direct (mapped cols)
//   blocks [5018,5249):  fold aux  (W_hh regions, bias col 209, zeros)
__global__ __launch_bounds__(256) void prep_kernel(
        const float* __restrict__ hv0, unsigned short* __restrict__ hf0,
        int* __restrict__ cnt, int* __restrict__ gcounter,
        const float* __restrict__ W_msg, const float* __restrict__ b_msg,
        const float* __restrict__ W_ih, const float* __restrict__ b_ih,
        const float* __restrict__ b_hh, const float* __restrict__ W_hh,
        unsigned short* __restrict__ Bhi, unsigned short* __restrict__ Blo) {
    int b = blockIdx.x;
    if (b < 5000) {
        int i = b * 256 + threadIdx.x;
        if (i < 2) gcounter[i] = 0;          // [0]=region base, [1]=hist done-count
        if (i < NC * NN) cnt[i] = 0;
        if (i < NN * 64) hf0[i] = f2h(hv0[i]);
        return;
    }
    if (b >= 5018) {
        // aux regions per t: n<192 & k<64 (12288), n<192 & k in [209,224)
        // (2880), n>=192 all k (14336) -> 29504 per t.
        int aidx = (b - 5018) * 256 + threadIdx.x;
        if (aidx >= 2 * 29504) return;
        int t = aidx / 29504, r = aidx % 29504;
        int n, k;
        if (r < 12288) { n = r >> 6; k = r & 63; }
        else if (r < 15168) { int q = r - 12288; n = q / 15; k = 209 + q % 15; }
        else { int q = r - 15168; n = 192 + q / 224; k = q % 224; }
        float v = 0.f;
        if (n < 192) {
            if (k < 64) {
                if (n < 128) v = W_hh[(size_t)t * 192 * 64 + n * 64 + k];
            } else if (k == 209) {
                v = (n < 128) ? (b_ih[t * 192 + n] + b_hh[t * 192 + n]) : b_ih[t * 192 + n];
            }
        } else {
            int j = n - 64;   // 128..191
            if (k < 64) v = W_hh[(size_t)t * 192 * 64 + j * 64 + k];
            else if (k == 209) v = b_hh[t * 192 + j];
        }
        unsigned short hi, lo;
        splitf(v, hi, lo);
        size_t o = ((size_t)t * 256 + n) * KA + k;
        Bhi[o] = hi;
        Blo[o] = lo;
        return;
    }
    // fold main: WcT[t][j][kw] -> B col map: kw<64 -> 128+kw ; 64..128 -> kw ;
    // 128..144 -> 64+kw (192..207); bacc -> col 208.
    __shared__ float ldsW[64][193];
    int fb = b - 5000;
    int t = fb / 9;
    int k0 = (fb % 9) * 16;
    int j = threadIdx.x;
    float acc[16];
#pragma unroll
    for (int kk = 0; kk < 16; ++kk) acc[kk] = 0.f;
    float bacc = 0.f;
    for (int mc = 0; mc < 2; ++mc) {
        for (int i = threadIdx.x; i < 192 * 64; i += 256) {
            int jj = i >> 6, mm = i & 63;
            ldsW[mm][jj] = W_ih[((size_t)t * 192 + jj) * 128 + mc * 64 + mm];
        }
        __syncthreads();
        if (j < 192) {
            for (int mm = 0; mm < 64; ++mm) {
                float wl = ldsW[mm][j];
                float bm = b_msg[t * 128 + mc * 64 + mm];
                bacc = fmaf(bm, wl, bacc);
#pragma unroll
                for (int kk = 0; kk < 16; ++kk) {
                    float wm = W_msg[((size_t)t * 144 + k0 + kk) * 128 + mc * 64 + mm];
                    acc[kk] = fmaf(wm, wl, acc[kk]);
                }
            }
        }
        __syncthreads();
    }
    if (j < 192) {
        size_t rowo = ((size_t)t * 256 + j) * KA;
#pragma unroll
        for (int kk = 0; kk < 16; ++kk) {
            int kw = k0 + kk;
            int bcol = (kw < 64) ? (128 + kw) : ((kw < 128) ? kw : (64 + kw));
            unsigned short hi, lo;
            splitf(acc[kk], hi, lo);
            Bhi[rowo + bcol] = hi;
            Blo[rowo + bcol] = lo;
        }
        if (k0 == 0) {
            unsigned short hi, lo;
            splitf(bacc, hi, lo);
            Bhi[rowo + 208] = hi;
            Blo[rowo + 208] = lo;
        }
    }
}

// hist + scan fused (R18 post-mortem: dispatch gaps ~10 µs each are the cost;
// this is the one remaining fusion with a SAFE waiter count).
// All NB_HIST blocks: histogram atomics, then increment done-counter.
// Blocks 0..NB_SCAN-1 additionally spin until done==NB_HIST, then run the scan
// phase. cnt is re-read via device-scope atomic loads (per-XCD L2 could hold
// stale zeroed lines from prep — G16). 79 waiters << residency: deadlock-free.
__global__ __launch_bounds__(256) void hist_scan_kernel(
        const int* __restrict__ dst, int* __restrict__ cnt,
        int* __restrict__ gcounter,
        int* __restrict__ row_ptr, int* __restrict__ deg,
        int* __restrict__ cursor) {
    int i = blockIdx.x * 256 + threadIdx.x;
    if (i < NE) atomicAdd(&cnt[(i / CHUNK) * NN + dst[i]], 1);
    __syncthreads();
    if (threadIdx.x == 0) {
        __threadfence();
        atomicAdd(&gcounter[1], 1);
    }
    if (blockIdx.x >= NB_SCAN) return;

    // wait for all histogram blocks
    if (threadIdx.x == 0) {
        while (atomicAdd(&gcounter[1], 0) < NB_HIST) { }
    }
    __syncthreads();

    __shared__ int s[256];
    __shared__ int base_sh;
    int t = threadIdx.x;
    int node = blockIdx.x * 256 + t;
    int cl[NC];
    int d = 0;
    if (node < NN) {
#pragma unroll
        for (int c = 0; c < NC; ++c) {
            cl[c] = atomicAdd(&cnt[c * NN + node], 0);   // coherent read
            d += cl[c];
        }
    }
    s[t] = d;
    __syncthreads();
    for (int off = 1; off < 256; off <<= 1) {
        int v = (t >= off) ? s[t - off] : 0;
        __syncthreads();
        s[t] += v;
        __syncthreads();
    }
    if (t == 255) base_sh = atomicAdd(&gcounter[0], s[255]);
    __syncthreads();
    if (node < NN) {
        int run = base_sh + s[t] - d;
        row_ptr[node] = run;
        deg[node] = d;
#pragma unroll
        for (int c = 0; c < NC; ++c) {
            cursor[c * NN + node] = run;
            run += cl[c];
        }
    }
}

__global__ void place_kernel(const int* __restrict__ src, const int* __restrict__ dst,
                             int* __restrict__ cursor, int2* __restrict__ adj) {
    int i = blockIdx.x * blockDim.x + threadIdx.x;
    if (i < NE) {
        int d = dst[i];
        int pos = atomicAdd(&cursor[(i / CHUNK) * NN + d], 1);
        adj[pos] = make_int2(src[i], i);
    }
}

// ---------------- per-round ----------------
// A[v][0:224) = [ h | S | deg*h | esum | deg | 1 | 0pad ]; only dgh gets hi/lo.
// FIRST=true also gathers edge features inline and writes A's round-invariant
// tail; FIRST=false skips the tail (persists in Ahi from round 0).
template <bool FIRST>
__global__ __launch_bounds__(256) void gather_kernel(
        const float* __restrict__ hv, const unsigned short* __restrict__ hf,
        const int* __restrict__ row_ptr, const int* __restrict__ degp,
        const int2* __restrict__ adj, const float* __restrict__ ef,
        unsigned short* __restrict__ Ahi, unsigned short* __restrict__ Alo) {
    int wid = threadIdx.x >> 6, lane = threadIdx.x & 63;
    int v = blockIdx.x * 4 + wid;
    if (v >= NN) return;
    int rp0 = row_ptr[v];
    int dgi = degp[v];
    int rp1 = rp0 + dgi;
    int q = lane >> 3;            // 8 edge slots
    int fo = (lane & 7) << 3;     // 8 halfs (16B) per lane
    float a0[8], a1[8], a2[8], a3[8];
#pragma unroll
    for (int j = 0; j < 8; ++j) { a0[j] = 0.f; a1[j] = 0.f; a2[j] = 0.f; a3[j] = 0.f; }
    int i = rp0 + q;
    for (; i + 24 < rp1; i += 32) {
        int s0 = adj[i].x, s1 = adj[i + 8].x, s2 = adj[i + 16].x, s3 = adj[i + 24].x;
        u16x8 x0 = *(const u16x8*)(hf + (size_t)s0 * 64 + fo);
        u16x8 x1 = *(const u16x8*)(hf + (size_t)s1 * 64 + fo);
        u16x8 x2 = *(const u16x8*)(hf + (size_t)s2 * 64 + fo);
        u16x8 x3 = *(const u16x8*)(hf + (size_t)s3 * 64 + fo);
#pragma unroll
        for (int j = 0; j < 8; ++j) {
            a0[j] += h2f(x0[j]); a1[j] += h2f(x1[j]);
            a2[j] += h2f(x2[j]); a3[j] += h2f(x3[j]);
        }
    }
    for (; i < rp1; i += 8) {
        int s = adj[i].x;
        u16x8 x = *(const u16x8*)(hf + (size_t)s * 64 + fo);
#pragma unroll
        for (int j = 0; j < 8; ++j) a0[j] += h2f(x[j]);
    }
#pragma unroll
    for (int j = 0; j < 8; ++j) a0[j] += a1[j] + a2[j] + a3[j];
#pragma unroll
    for (int m = 8; m < 64; m <<= 1)
#pragma unroll
        for (int j = 0; j < 8; ++j) a0[j] += __shfl_xor(a0[j], m);
    float dg = (float)dgi;
    if (lane < 8) {
        float4 hA = *(const float4*)(hv + (size_t)v * 64 + lane * 8);
        float4 hB = *(const float4*)(hv + (size_t)v * 64 + lane * 8 + 4);
        float h8[8] = {hA.x, hA.y, hA.z, hA.w, hB.x, hB.y, hB.z, hB.w};
        u16x8 hh, sh, dh, dl;
#pragma unroll
        for (int j = 0; j < 8; ++j) {
            hh[j] = f2h(h8[j]);
            sh[j] = f2h(a0[j]);
            unsigned short thi, tlo;
            splitf(dg * h8[j], thi, tlo);
            dh[j] = thi; dl[j] = tlo;
        }
        *(u16x8*)(Ahi + (size_t)v * KA + fo) = hh;
        *(u16x8*)(Ahi + (size_t)v * KA + 64 + fo) = sh;
        *(u16x8*)(Ahi + (size_t)v * KA + 128 + fo) = dh;
        *(u16x8*)(Alo + (size_t)v * KA + 128 + fo) = dl;
    }
    if (FIRST) {
        // edge-feature gather: 16 slots x 4 lanes x float4
        int fo2 = (lane & 3) << 2;
        float4 e = make_float4(0.f, 0.f, 0.f, 0.f);
        for (int ii = rp0 + (lane >> 2); ii < rp1; ii += 16) {
            int eid = adj[ii].y;
            float4 x = *(const float4*)(ef + (size_t)eid * 16 + fo2);
            e.x += x.x; e.y += x.y; e.z += x.z; e.w += x.w;
        }
#pragma unroll
        for (int m = 4; m < 64; m <<= 1) {
            e.x += __shfl_xor(e.x, m);
            e.y += __shfl_xor(e.y, m);
            e.z += __shfl_xor(e.z, m);
            e.w += __shfl_xor(e.w, m);
        }
        if (lane < 4) {
            u16x4 tv;
            tv[0] = f2h(e.x); tv[1] = f2h(e.y);
            tv[2] = f2h(e.z); tv[3] = f2h(e.w);
            *(u16x4*)(Ahi + (size_t)v * KA + 192 + lane * 4) = tv;
        } else if (lane == 4) {
            u16x8 tv;
#pragma unroll
            for (int j = 0; j < 8; ++j) tv[j] = 0;
            tv[0] = f2h(dg);
            tv[1] = f2h(1.f);
            *(u16x8*)(Ahi + (size_t)v * KA + 208) = tv;
        } else if (lane == 5) {
            u16x8 tv;
#pragma unroll
            for (int j = 0; j < 8; ++j) tv[j] = 0;
            *(u16x8*)(Ahi + (size_t)v * KA + 216) = tv;
        }
    }
}

// Fused MFMA GEMM (64x256 tile, 256 thr, grid 314) + in-register GRU gates.
// Selective precision (R14, frozen) + zero-block fn skips:
//   phases 0-1 (h):    1 MFMA, fn in {0..7, 12..15}
//   phases 2-3 (S):    1 MFMA, fn in {0..11}
//   phases 4-5 (dgh):  3 MFMA, fn in {0..11}
//   phase  6  (tail):  2 MFMA, fn in {0..15}
__global__ __launch_bounds__(256) void gemm_gru(
        const _Float16* __restrict__ Ahi, const _Float16* __restrict__ Alo,
        const _Float16* __restrict__ Bhi, const _Float16* __restrict__ Blo,
        const float* __restrict__ hin,
        float* __restrict__ fout, unsigned short* __restrict__ hfout) {
    __shared__ _Float16 Ash[64][40];    // +8 pad
    __shared__ _Float16 Asl[64][40];
    __shared__ _Float16 Bsh[256][40];
    __shared__ _Float16 Bsl[256][40];
    int tid = threadIdx.x;
    int w = tid >> 6, l = tid & 63;
    int row0 = blockIdx.x * 64;
    f32x4 acc[16];
#pragma unroll
    for (int i = 0; i < 16; ++i) acc[i] = (f32x4){0.f, 0.f, 0.f, 0.f};

    int sAr = tid >> 2, sAc = (tid & 3) * 8;
    int kg = (l >> 4) * 8;
    int ar = w * 16 + (l & 15);
    int lc = l & 15;

    // ---- phases 0-1: h block — hi only, 1 MFMA, skip fn 8-11 ----
#pragma unroll 1
    for (int ks = 0; ks < 2; ++ks) {
        int k0 = ks * 32;
        *(float4*)&Ash[sAr][sAc] = *(const float4*)(Ahi + (size_t)(row0 + sAr) * KA + k0 + sAc);
        {
            const float4* ph = (const float4*)(Bhi + (size_t)tid * KA + k0);
            float4 h0 = ph[0], h1 = ph[1], h2 = ph[2], h3 = ph[3];
            *(float4*)&Bsh[tid][0] = h0;  *(float4*)&Bsh[tid][8] = h1;
            *(float4*)&Bsh[tid][16] = h2; *(float4*)&Bsh[tid][24] = h3;
        }
        __syncthreads();
        f16x8 ah = *(const f16x8*)&Ash[ar][kg];
#pragma unroll
        for (int fn = 0; fn < 8; ++fn) {
            f16x8 bh = *(const f16x8*)&Bsh[fn * 16 + lc][kg];
            acc[fn] = __builtin_amdgcn_mfma_f32_16x16x32_f16(ah, bh, acc[fn], 0, 0, 0);
        }
#pragma unroll
        for (int fn = 12; fn < 16; ++fn) {
            f16x8 bh = *(const f16x8*)&Bsh[fn * 16 + lc][kg];
            acc[fn] = __builtin_amdgcn_mfma_f32_16x16x32_f16(ah, bh, acc[fn], 0, 0, 0);
        }
        __syncthreads();
    }

    // ---- phases 2-3: S block — hi only, 1 MFMA, fn 0-11 ----
#pragma unroll 1
    for (int ks = 2; ks < 4; ++ks) {
        int k0 = ks * 32;
        *(float4*)&Ash[sAr][sAc] = *(const float4*)(Ahi + (size_t)(row0 + sAr) * KA + k0 + sAc);
        {
            const float4* ph = (const float4*)(Bhi + (size_t)tid * KA + k0);
            float4 h0 = ph[0], h1 = ph[1], h2 = ph[2], h3 = ph[3];
            *(float4*)&Bsh[tid][0] = h0;  *(float4*)&Bsh[tid][8] = h1;
            *(float4*)&Bsh[tid][16] = h2; *(float4*)&Bsh[tid][24] = h3;
        }
        __syncthreads();
        f16x8 ah = *(const f16x8*)&Ash[ar][kg];
#pragma unroll
        for (int fn = 0; fn < 12; ++fn) {
            f16x8 bh = *(const f16x8*)&Bsh[fn * 16 + lc][kg];
            acc[fn] = __builtin_amdgcn_mfma_f32_16x16x32_f16(ah, bh, acc[fn], 0, 0, 0);
        }
        __syncthreads();
    }

    // ---- phases 4-5: dgh block — full hi/lo, 3 MFMA, fn 0-11 ----
#pragma unroll 1
    for (int ks = 4; ks < 6; ++ks) {
        int k0 = ks * 32;
        *(float4*)&Ash[sAr][sAc] = *(const float4*)(Ahi + (size_t)(row0 + sAr) * KA + k0 + sAc);
        *(float4*)&Asl[sAr][sAc] = *(const float4*)(Alo + (size_t)(row0 + sAr) * KA + k0 + sAc);
        {
            const float4* ph = (const float4*)(Bhi + (size_t)tid * KA + k0);
            float4 h0 = ph[0], h1 = ph[1], h2 = ph[2], h3 = ph[3];
            *(float4*)&Bsh[tid][0] = h0;  *(float4*)&Bsh[tid][8] = h1;
            *(float4*)&Bsh[tid][16] = h2; *(float4*)&Bsh[tid][24] = h3;
            const float4* pl = (const float4*)(Blo + (size_t)tid * KA + k0);
            float4 l0 = pl[0], l1 = pl[1], l2 = pl[2], l3 = pl[3];
            *(float4*)&Bsl[tid][0] = l0;  *(float4*)&Bsl[tid][8] = l1;
            *(float4*)&Bsl[tid][16] = l2; *(float4*)&Bsl[tid][24] = l3;
        }
        __syncthreads();
        f16x8 ah = *(const f16x8*)&Ash[ar][kg];
        f16x8 al = *(const f16x8*)&Asl[ar][kg];
#pragma unroll
        for (int fn = 0; fn < 12; ++fn) {
            f16x8 bh = *(const f16x8*)&Bsh[fn * 16 + lc][kg];
            f16x8 bl = *(const f16x8*)&Bsl[fn * 16 + lc][kg];
            acc[fn] = __builtin_amdgcn_mfma_f32_16x16x32_f16(ah, bh, acc[fn], 0, 0, 0);
            acc[fn] = __builtin_amdgcn_mfma_f32_16x16x32_f16(ah, bl, acc[fn], 0, 0, 0);
            acc[fn] = __builtin_amdgcn_mfma_f32_16x16x32_f16(al, bh, acc[fn], 0, 0, 0);
        }
        __syncthreads();
    }

    // ---- phase 6: tail (esum/deg/1/bias) — 2 MFMA, all fn ----
    {
        const int k0 = 192;
        *(float4*)&Ash[sAr][sAc] = *(const float4*)(Ahi + (size_t)(row0 + sAr) * KA + k0 + sAc);
        {
            const float4* ph = (const float4*)(Bhi + (size_t)tid * KA + k0);
            float4 h0 = ph[0], h1 = ph[1], h2 = ph[2], h3 = ph[3];
            *(float4*)&Bsh[tid][0] = h0;  *(float4*)&Bsh[tid][8] = h1;
            *(float4*)&Bsh[tid][16] = h2; *(float4*)&Bsh[tid][24] = h3;
            const float4* pl = (const float4*)(Blo + (size_t)tid * KA + k0);
            float4 l0 = pl[0], l1 = pl[1], l2 = pl[2], l3 = pl[3];
            *(float4*)&Bsl[tid][0] = l0;  *(float4*)&Bsl[tid][8] = l1;
            *(float4*)&Bsl[tid][16] = l2; *(float4*)&Bsl[tid][24] = l3;
        }
        __syncthreads();
        f16x8 ah = *(const f16x8*)&Ash[ar][kg];
#pragma unroll
        for (int fn = 0; fn < 16; ++fn) {
            f16x8 bh = *(const f16x8*)&Bsh[fn * 16 + lc][kg];
            f16x8 bl = *(const f16x8*)&Bsl[fn * 16 + lc][kg];
            acc[fn] = __builtin_amdgcn_mfma_f32_16x16x32_f16(ah, bh, acc[fn], 0, 0, 0);
            acc[fn] = __builtin_amdgcn_mfma_f32_16x16x32_f16(ah, bl, acc[fn], 0, 0, 0);
        }
        __syncthreads();
    }

    // epilogue
    int jb = l & 15;
#pragma unroll
    for (int q = 0; q < 4; ++q) {
        int row = row0 + w * 16 + (l >> 4) * 4 + q;
        if (row >= NN) continue;
#pragma unroll
        for (int fj = 0; fj < 4; ++fj) {
            int j = jb + fj * 16;
            float rr = acc[fj][q];
            float zz = acc[4 + fj][q];
            float in_ = acc[8 + fj][q];
            float hn = acc[12 + fj][q];
            float r = 1.f / (1.f + __expf(-rr));
            float z = 1.f / (1.f + __expf(-zz));
            float n = tanhf(in_ + r * hn);
            float h = hin[(size_t)row * 64 + j];
            float val = (1.f - z) * n + z * h;
            fout[(size_t)row * 64 + j] = val;
            hfout[(size_t)row * 64 + j] = f2h(val);
        }
    }
}

extern "C" void kernel_launch(void* const* d_in, const int* in_sizes, int n_in,
                              void* d_out, int out_size, void* d_ws, size_t ws_size,
                              hipStream_t stream) {
    const float* hv0   = (const float*)d_in[0];
    const float* ef    = (const float*)d_in[1];
    const int*   src   = (const int*)d_in[2];
    const int*   dst   = (const int*)d_in[3];
    const float* W_msg = (const float*)d_in[4];
    const float* b_msg = (const float*)d_in[5];
    const float* W_ih  = (const float*)d_in[6];
    const float* W_hh  = (const float*)d_in[7];
    const float* b_ih  = (const float*)d_in[8];
    const float* b_hh  = (const float*)d_in[9];
    float* out = (float*)d_out;

    char* ws = (char*)d_ws;
    size_t off = 0;
    auto alloc = [&](size_t bytes) -> char* {
        char* p = ws + off;
        off = (off + bytes + 255) & ~(size_t)255;
        return p;
    };
    int*   cnt      = (int*)alloc((size_t)NC * NN * 4);
    int*   row_ptr  = (int*)alloc(NN * 4);
    int*   deg      = (int*)alloc(NN * 4);
    int*   cursor   = (int*)alloc((size_t)NC * NN * 4);
    int*   gcounter = (int*)alloc(8);   // [0]=region base, [1]=hist done-count
    int2*  adj      = (int2*)alloc((size_t)NE * 8);
    unsigned short* Ahi = (unsigned short*)alloc((size_t)MP * KA * 2);
    unsigned short* Alo = (unsigned short*)alloc((size_t)MP * KA * 2);
    unsigned short* Bhi = (unsigned short*)alloc((size_t)2 * 256 * KA * 2);
    unsigned short* Blo = (unsigned short*)alloc((size_t)2 * 256 * KA * 2);
    float* hv1      = (float*)alloc((size_t)NN * 64 * 4);
    unsigned short* hf0 = (unsigned short*)alloc((size_t)NN * 64 * 2);
    unsigned short* hf1 = (unsigned short*)alloc((size_t)NN * 64 * 2);

    // 5000 init blocks + 18 fold-main + 231 fold-aux
    prep_kernel<<<5000 + 18 + (2 * 29504 + 255) / 256, 256, 0, stream>>>(
        hv0, hf0, cnt, gcounter, W_msg, b_msg, W_ih, b_ih, b_hh, W_hh, Bhi, Blo);
    hist_scan_kernel<<<NB_HIST, 256, 0, stream>>>(dst, cnt, gcounter,
                                                  row_ptr, deg, cursor);
    place_kernel<<<(NE + 255) / 256, 256, 0, stream>>>(src, dst, cursor, adj);

    // round 0 (gather also computes esum inline + writes A tail)
    gather_kernel<true><<<(NN + 3) / 4, 256, 0, stream>>>(
        hv0, hf0, row_ptr, deg, adj, ef, Ahi, Alo);
    gemm_gru<<<MP / 64, 256, 0, stream>>>(
        (const _Float16*)Ahi, (const _Float16*)Alo,
        (const _Float16*)Bhi, (const _Float16*)Blo,
        hv0, hv1, hf1);
    // round 1 (tail persists in Ahi)
    gather_kernel<false><<<(NN + 3) / 4, 256, 0, stream>>>(
        hv1, hf1, row_ptr, deg, adj, ef, Ahi, Alo);
    gemm_gru<<<MP / 64, 256, 0, stream>>>(
        (const _Float16*)Ahi, (const _Float16*)Alo,
        (const _Float16*)(Bhi + (size_t)256 * KA),
        (const _Float16*)(Blo + (size_t)256 * KA),
        hv1, out, hf1);
}

// Round 20
// 181.726 us; speedup vs baseline: 1.3649x; 1.3649x over previous
//
#include <hip/hip_runtime.h>
#include <cstddef>
#include <cstdint>

#define NN 20000
#define NE 640000
#define MP 20096       // padded rows (314*64)
#define KA 224         // A row length (halfs)
#define NC 16
#define CHUNK 40000    // NE / NC
#define NB_SCAN 79     // ceil(NN/256)

typedef _Float16 f16x8 __attribute__((ext_vector_type(8)));
typedef float f32x4 __attribute__((ext_vector_type(4)));
typedef unsigned short u16x8 __attribute__((ext_vector_type(8)));
typedef unsigned short u16x4 __attribute__((ext_vector_type(4)));

__device__ __forceinline__ float h2f(unsigned short u) {
    _Float16 h;
    *reinterpret_cast<unsigned short*>(&h) = u;
    return (float)h;
}
__device__ __forceinline__ unsigned short f2h(float f) {
    _Float16 h = (_Float16)f;
    return *reinterpret_cast<unsigned short*>(&h);
}
// fp16 two-term split: x ~= hi + lo (22 effective mantissa bits)
__device__ __forceinline__ void splitf(float x, unsigned short& hi, unsigned short& lo) {
    _Float16 h = (_Float16)x;
    _Float16 l = (_Float16)(x - (float)h);
    hi = *reinterpret_cast<unsigned short*>(&h);
    lo = *reinterpret_cast<unsigned short*>(&l);
}

// ---------------- setup ----------------
// ONE prep kernel:
//   blocks [0,5000):     zero cnt (+gcounter) + build fp16 h table
//   blocks [5000,5018):  fold main (t, k0-chunk) -> B direct (mapped cols)
//   blocks [5018,5249):  fold aux  (W_hh regions, bias col 209, zeros)
__global__ __launch_bounds__(256) void prep_kernel(
        const float* __restrict__ hv0, unsigned short* __restrict__ hf0,
        int* __restrict__ cnt, int* __restrict__ gcounter,
        const float* __restrict__ W_msg, const float* __restrict__ b_msg,
        const float* __restrict__ W_ih, const float* __restrict__ b_ih,
        const float* __restrict__ b_hh, const float* __restrict__ W_hh,
        unsigned short* __restrict__ Bhi, unsigned short* __restrict__ Blo) {
    int b = blockIdx.x;
    if (b < 5000) {
        int i = b * 256 + threadIdx.x;
        if (i == 0) *gcounter = 0;
        if (i < NC * NN) cnt[i] = 0;
        if (i < NN * 64) hf0[i] = f2h(hv0[i]);
        return;
    }
    if (b >= 5018) {
        // aux regions per t: n<192 & k<64 (12288), n<192 & k in [209,224)
        // (2880), n>=192 all k (14336) -> 29504 per t.
        int aidx = (b - 5018) * 256 + threadIdx.x;
        if (aidx >= 2 * 29504) return;
        int t = aidx / 29504, r = aidx % 29504;
        int n, k;
        if (r < 12288) { n = r >> 6; k = r & 63; }
        else if (r < 15168) { int q = r - 12288; n = q / 15; k = 209 + q % 15; }
        else { int q = r - 15168; n = 192 + q / 224; k = q % 224; }
        float v = 0.f;
        if (n < 192) {
            if (k < 64) {
                if (n < 128) v = W_hh[(size_t)t * 192 * 64 + n * 64 + k];
            } else if (k == 209) {
                v = (n < 128) ? (b_ih[t * 192 + n] + b_hh[t * 192 + n]) : b_ih[t * 192 + n];
            }
        } else {
            int j = n - 64;   // 128..191
            if (k < 64) v = W_hh[(size_t)t * 192 * 64 + j * 64 + k];
            else if (k == 209) v = b_hh[t * 192 + j];
        }
        unsigned short hi, lo;
        splitf(v, hi, lo);
        size_t o = ((size_t)t * 256 + n) * KA + k;
        Bhi[o] = hi;
        Blo[o] = lo;
        return;
    }
    // fold main: WcT[t][j][kw] -> B col map: kw<64 -> 128+kw ; 64..128 -> kw ;
    // 128..144 -> 64+kw (192..207); bacc -> col 208.
    __shared__ float ldsW[64][193];
    int fb = b - 5000;
    int t = fb / 9;
    int k0 = (fb % 9) * 16;
    int j = threadIdx.x;
    float acc[16];
#pragma unroll
    for (int kk = 0; kk < 16; ++kk) acc[kk] = 0.f;
    float bacc = 0.f;
    for (int mc = 0; mc < 2; ++mc) {
        for (int i = threadIdx.x; i < 192 * 64; i += 256) {
            int jj = i >> 6, mm = i & 63;
            ldsW[mm][jj] = W_ih[((size_t)t * 192 + jj) * 128 + mc * 64 + mm];
        }
        __syncthreads();
        if (j < 192) {
            for (int mm = 0; mm < 64; ++mm) {
                float wl = ldsW[mm][j];
                float bm = b_msg[t * 128 + mc * 64 + mm];
                bacc = fmaf(bm, wl, bacc);
#pragma unroll
                for (int kk = 0; kk < 16; ++kk) {
                    float wm = W_msg[((size_t)t * 144 + k0 + kk) * 128 + mc * 64 + mm];
                    acc[kk] = fmaf(wm, wl, acc[kk]);
                }
            }
        }
        __syncthreads();
    }
    if (j < 192) {
        size_t rowo = ((size_t)t * 256 + j) * KA;
#pragma unroll
        for (int kk = 0; kk < 16; ++kk) {
            int kw = k0 + kk;
            int bcol = (kw < 64) ? (128 + kw) : ((kw < 128) ? kw : (64 + kw));
            unsigned short hi, lo;
            splitf(acc[kk], hi, lo);
            Bhi[rowo + bcol] = hi;
            Blo[rowo + bcol] = lo;
        }
        if (k0 == 0) {
            unsigned short hi, lo;
            splitf(bacc, hi, lo);
            Bhi[rowo + 208] = hi;
            Blo[rowo + 208] = lo;
        }
    }
}

__global__ void hist_kernel(const int* __restrict__ dst, int* __restrict__ cnt) {
    int i = blockIdx.x * blockDim.x + threadIdx.x;
    if (i < NE) atomicAdd(&cnt[(i / CHUNK) * NN + dst[i]], 1);
}

// Single-dispatch scan: per-block local LDS scan + ONE atomicAdd for the block
// base — regions land in arbitrary block order, which nothing downstream
// depends on (gather uses row_ptr[v] + deg[v]; within-node edge ordering
// unchanged -> sums identical).
// NOTE (R19 post-mortem): do NOT fuse hist into this with a spin barrier —
// 79 spinning blocks hammering one atomic line throttled the hist atomics
// themselves (105 µs vs 25 µs separate).
__global__ __launch_bounds__(256) void scan_kernel(const int* __restrict__ cnt,
                                                   int* __restrict__ gcounter,
                                                   int* __restrict__ row_ptr,
                                                   int* __restrict__ deg,
                                                   int* __restrict__ cursor) {
    __shared__ int s[256];
    __shared__ int base_sh;
    int t = threadIdx.x;
    int i = blockIdx.x * 256 + t;
    int d = 0;
    if (i < NN)
#pragma unroll
        for (int c = 0; c < NC; ++c) d += cnt[c * NN + i];
    s[t] = d;
    __syncthreads();
    for (int off = 1; off < 256; off <<= 1) {
        int v = (t >= off) ? s[t - off] : 0;
        __syncthreads();
        s[t] += v;
        __syncthreads();
    }
    if (t == 255) base_sh = atomicAdd(gcounter, s[255]);
    __syncthreads();
    if (i < NN) {
        int run = base_sh + s[t] - d;
        row_ptr[i] = run;
        deg[i] = d;
#pragma unroll
        for (int c = 0; c < NC; ++c) {
            cursor[c * NN + i] = run;
            run += cnt[c * NN + i];
        }
    }
}

__global__ void place_kernel(const int* __restrict__ src, const int* __restrict__ dst,
                             int* __restrict__ cursor, int2* __restrict__ adj) {
    int i = blockIdx.x * blockDim.x + threadIdx.x;
    if (i < NE) {
        int d = dst[i];
        int pos = atomicAdd(&cursor[(i / CHUNK) * NN + d], 1);
        adj[pos] = make_int2(src[i], i);
    }
}

// ---------------- per-round ----------------
// A[v][0:224) = [ h | S | deg*h | esum | deg | 1 | 0pad ]; only dgh gets hi/lo.
// FIRST=true also gathers edge features inline and writes A's round-invariant
// tail; FIRST=false skips the tail (persists in Ahi from round 0).
template <bool FIRST>
__global__ __launch_bounds__(256) void gather_kernel(
        const float* __restrict__ hv, const unsigned short* __restrict__ hf,
        const int* __restrict__ row_ptr, const int* __restrict__ degp,
        const int2* __restrict__ adj, const float* __restrict__ ef,
        unsigned short* __restrict__ Ahi, unsigned short* __restrict__ Alo) {
    int wid = threadIdx.x >> 6, lane = threadIdx.x & 63;
    int v = blockIdx.x * 4 + wid;
    if (v >= NN) return;
    int rp0 = row_ptr[v];
    int dgi = degp[v];
    int rp1 = rp0 + dgi;
    int q = lane >> 3;            // 8 edge slots
    int fo = (lane & 7) << 3;     // 8 halfs (16B) per lane
    float a0[8], a1[8], a2[8], a3[8];
#pragma unroll
    for (int j = 0; j < 8; ++j) { a0[j] = 0.f; a1[j] = 0.f; a2[j] = 0.f; a3[j] = 0.f; }
    int i = rp0 + q;
    for (; i + 24 < rp1; i += 32) {
        int s0 = adj[i].x, s1 = adj[i + 8].x, s2 = adj[i + 16].x, s3 = adj[i + 24].x;
        u16x8 x0 = *(const u16x8*)(hf + (size_t)s0 * 64 + fo);
        u16x8 x1 = *(const u16x8*)(hf + (size_t)s1 * 64 + fo);
        u16x8 x2 = *(const u16x8*)(hf + (size_t)s2 * 64 + fo);
        u16x8 x3 = *(const u16x8*)(hf + (size_t)s3 * 64 + fo);
#pragma unroll
        for (int j = 0; j < 8; ++j) {
            a0[j] += h2f(x0[j]); a1[j] += h2f(x1[j]);
            a2[j] += h2f(x2[j]); a3[j] += h2f(x3[j]);
        }
    }
    for (; i < rp1; i += 8) {
        int s = adj[i].x;
        u16x8 x = *(const u16x8*)(hf + (size_t)s * 64 + fo);
#pragma unroll
        for (int j = 0; j < 8; ++j) a0[j] += h2f(x[j]);
    }
#pragma unroll
    for (int j = 0; j < 8; ++j) a0[j] += a1[j] + a2[j] + a3[j];
#pragma unroll
    for (int m = 8; m < 64; m <<= 1)
#pragma unroll
        for (int j = 0; j < 8; ++j) a0[j] += __shfl_xor(a0[j], m);
    float dg = (float)dgi;
    if (lane < 8) {
        float4 hA = *(const float4*)(hv + (size_t)v * 64 + lane * 8);
        float4 hB = *(const float4*)(hv + (size_t)v * 64 + lane * 8 + 4);
        float h8[8] = {hA.x, hA.y, hA.z, hA.w, hB.x, hB.y, hB.z, hB.w};
        u16x8 hh, sh, dh, dl;
#pragma unroll
        for (int j = 0; j < 8; ++j) {
            hh[j] = f2h(h8[j]);
            sh[j] = f2h(a0[j]);
            unsigned short thi, tlo;
            splitf(dg * h8[j], thi, tlo);
            dh[j] = thi; dl[j] = tlo;
        }
        *(u16x8*)(Ahi + (size_t)v * KA + fo) = hh;
        *(u16x8*)(Ahi + (size_t)v * KA + 64 + fo) = sh;
        *(u16x8*)(Ahi + (size_t)v * KA + 128 + fo) = dh;
        *(u16x8*)(Alo + (size_t)v * KA + 128 + fo) = dl;
    }
    if (FIRST) {
        // edge-feature gather: 16 slots x 4 lanes x float4
        int fo2 = (lane & 3) << 2;
        float4 e = make_float4(0.f, 0.f, 0.f, 0.f);
        for (int ii = rp0 + (lane >> 2); ii < rp1; ii += 16) {
            int eid = adj[ii].y;
            float4 x = *(const float4*)(ef + (size_t)eid * 16 + fo2);
            e.x += x.x; e.y += x.y; e.z += x.z; e.w += x.w;
        }
#pragma unroll
        for (int m = 4; m < 64; m <<= 1) {
            e.x += __shfl_xor(e.x, m);
            e.y += __shfl_xor(e.y, m);
            e.z += __shfl_xor(e.z, m);
            e.w += __shfl_xor(e.w, m);
        }
        if (lane < 4) {
            u16x4 tv;
            tv[0] = f2h(e.x); tv[1] = f2h(e.y);
            tv[2] = f2h(e.z); tv[3] = f2h(e.w);
            *(u16x4*)(Ahi + (size_t)v * KA + 192 + lane * 4) = tv;
        } else if (lane == 4) {
            u16x8 tv;
#pragma unroll
            for (int j = 0; j < 8; ++j) tv[j] = 0;
            tv[0] = f2h(dg);
            tv[1] = f2h(1.f);
            *(u16x8*)(Ahi + (size_t)v * KA + 208) = tv;
        } else if (lane == 5) {
            u16x8 tv;
#pragma unroll
            for (int j = 0; j < 8; ++j) tv[j] = 0;
            *(u16x8*)(Ahi + (size_t)v * KA + 216) = tv;
        }
    }
}

// Fused MFMA GEMM (64x256 tile, 256 thr, grid 314) + in-register GRU gates.
// Selective precision (R14, frozen) + zero-block fn skips:
//   phases 0-1 (h):    1 MFMA, fn in {0..7, 12..15}
//   phases 2-3 (S):    1 MFMA, fn in {0..11}
//   phases 4-5 (dgh):  3 MFMA, fn in {0..11}
//   phase  6  (tail):  2 MFMA, fn in {0..15}
__global__ __launch_bounds__(256) void gemm_gru(
        const _Float16* __restrict__ Ahi, const _Float16* __restrict__ Alo,
        const _Float16* __restrict__ Bhi, const _Float16* __restrict__ Blo,
        const float* __restrict__ hin,
        float* __restrict__ fout, unsigned short* __restrict__ hfout) {
    __shared__ _Float16 Ash[64][40];    // +8 pad
    __shared__ _Float16 Asl[64][40];
    __shared__ _Float16 Bsh[256][40];
    __shared__ _Float16 Bsl[256][40];
    int tid = threadIdx.x;
    int w = tid >> 6, l = tid & 63;
    int row0 = blockIdx.x * 64;
    f32x4 acc[16];
#pragma unroll
    for (int i = 0; i < 16; ++i) acc[i] = (f32x4){0.f, 0.f, 0.f, 0.f};

    int sAr = tid >> 2, sAc = (tid & 3) * 8;
    int kg = (l >> 4) * 8;
    int ar = w * 16 + (l & 15);
    int lc = l & 15;

    // ---- phases 0-1: h block — hi only, 1 MFMA, skip fn 8-11 ----
#pragma unroll 1
    for (int ks = 0; ks < 2; ++ks) {
        int k0 = ks * 32;
        *(float4*)&Ash[sAr][sAc] = *(const float4*)(Ahi + (size_t)(row0 + sAr) * KA + k0 + sAc);
        {
            const float4* ph = (const float4*)(Bhi + (size_t)tid * KA + k0);
            float4 h0 = ph[0], h1 = ph[1], h2 = ph[2], h3 = ph[3];
            *(float4*)&Bsh[tid][0] = h0;  *(float4*)&Bsh[tid][8] = h1;
            *(float4*)&Bsh[tid][16] = h2; *(float4*)&Bsh[tid][24] = h3;
        }
        __syncthreads();
        f16x8 ah = *(const f16x8*)&Ash[ar][kg];
#pragma unroll
        for (int fn = 0; fn < 8; ++fn) {
            f16x8 bh = *(const f16x8*)&Bsh[fn * 16 + lc][kg];
            acc[fn] = __builtin_amdgcn_mfma_f32_16x16x32_f16(ah, bh, acc[fn], 0, 0, 0);
        }
#pragma unroll
        for (int fn = 12; fn < 16; ++fn) {
            f16x8 bh = *(const f16x8*)&Bsh[fn * 16 + lc][kg];
            acc[fn] = __builtin_amdgcn_mfma_f32_16x16x32_f16(ah, bh, acc[fn], 0, 0, 0);
        }
        __syncthreads();
    }

    // ---- phases 2-3: S block — hi only, 1 MFMA, fn 0-11 ----
#pragma unroll 1
    for (int ks = 2; ks < 4; ++ks) {
        int k0 = ks * 32;
        *(float4*)&Ash[sAr][sAc] = *(const float4*)(Ahi + (size_t)(row0 + sAr) * KA + k0 + sAc);
        {
            const float4* ph = (const float4*)(Bhi + (size_t)tid * KA + k0);
            float4 h0 = ph[0], h1 = ph[1], h2 = ph[2], h3 = ph[3];
            *(float4*)&Bsh[tid][0] = h0;  *(float4*)&Bsh[tid][8] = h1;
            *(float4*)&Bsh[tid][16] = h2; *(float4*)&Bsh[tid][24] = h3;
        }
        __syncthreads();
        f16x8 ah = *(const f16x8*)&Ash[ar][kg];
#pragma unroll
        for (int fn = 0; fn < 12; ++fn) {
            f16x8 bh = *(const f16x8*)&Bsh[fn * 16 + lc][kg];
            acc[fn] = __builtin_amdgcn_mfma_f32_16x16x32_f16(ah, bh, acc[fn], 0, 0, 0);
        }
        __syncthreads();
    }

    // ---- phases 4-5: dgh block — full hi/lo, 3 MFMA, fn 0-11 ----
#pragma unroll 1
    for (int ks = 4; ks < 6; ++ks) {
        int k0 = ks * 32;
        *(float4*)&Ash[sAr][sAc] = *(const float4*)(Ahi + (size_t)(row0 + sAr) * KA + k0 + sAc);
        *(float4*)&Asl[sAr][sAc] = *(const float4*)(Alo + (size_t)(row0 + sAr) * KA + k0 + sAc);
        {
            const float4* ph = (const float4*)(Bhi + (size_t)tid * KA + k0);
            float4 h0 = ph[0], h1 = ph[1], h2 = ph[2], h3 = ph[3];
            *(float4*)&Bsh[tid][0] = h0;  *(float4*)&Bsh[tid][8] = h1;
            *(float4*)&Bsh[tid][16] = h2; *(float4*)&Bsh[tid][24] = h3;
            const float4* pl = (const float4*)(Blo + (size_t)tid * KA + k0);
            float4 l0 = pl[0], l1 = pl[1], l2 = pl[2], l3 = pl[3];
            *(float4*)&Bsl[tid][0] = l0;  *(float4*)&Bsl[tid][8] = l1;
            *(float4*)&Bsl[tid][16] = l2; *(float4*)&Bsl[tid][24] = l3;
        }
        __syncthreads();
        f16x8 ah = *(const f16x8*)&Ash[ar][kg];
        f16x8 al = *(const f16x8*)&Asl[ar][kg];
#pragma unroll
        for (int fn = 0; fn < 12; ++fn) {
            f16x8 bh = *(const f16x8*)&Bsh[fn * 16 + lc][kg];
            f16x8 bl = *(const f16x8*)&Bsl[fn * 16 + lc][kg];
            acc[fn] = __builtin_amdgcn_mfma_f32_16x16x32_f16(ah, bh, acc[fn], 0, 0, 0);
            acc[fn] = __builtin_amdgcn_mfma_f32_16x16x32_f16(ah, bl, acc[fn], 0, 0, 0);
            acc[fn] = __builtin_amdgcn_mfma_f32_16x16x32_f16(al, bh, acc[fn], 0, 0, 0);
        }
        __syncthreads();
    }

    // ---- phase 6: tail (esum/deg/1/bias) — 2 MFMA, all fn ----
    {
        const int k0 = 192;
        *(float4*)&Ash[sAr][sAc] = *(const float4*)(Ahi + (size_t)(row0 + sAr) * KA + k0 + sAc);
        {
            const float4* ph = (const float4*)(Bhi + (size_t)tid * KA + k0);
            float4 h0 = ph[0], h1 = ph[1], h2 = ph[2], h3 = ph[3];
            *(float4*)&Bsh[tid][0] = h0;  *(float4*)&Bsh[tid][8] = h1;
            *(float4*)&Bsh[tid][16] = h2; *(float4*)&Bsh[tid][24] = h3;
            const float4* pl = (const float4*)(Blo + (size_t)tid * KA + k0);
            float4 l0 = pl[0], l1 = pl[1], l2 = pl[2], l3 = pl[3];
            *(float4*)&Bsl[tid][0] = l0;  *(float4*)&Bsl[tid][8] = l1;
            *(float4*)&Bsl[tid][16] = l2; *(float4*)&Bsl[tid][24] = l3;
        }
        __syncthreads();
        f16x8 ah = *(const f16x8*)&Ash[ar][kg];
#pragma unroll
        for (int fn = 0; fn < 16; ++fn) {
            f16x8 bh = *(const f16x8*)&Bsh[fn * 16 + lc][kg];
            f16x8 bl = *(const f16x8*)&Bsl[fn * 16 + lc][kg];
            acc[fn] = __builtin_amdgcn_mfma_f32_16x16x32_f16(ah, bh, acc[fn], 0, 0, 0);
            acc[fn] = __builtin_amdgcn_mfma_f32_16x16x32_f16(ah, bl, acc[fn], 0, 0, 0);
        }
        __syncthreads();
    }

    // epilogue
    int jb = l & 15;
#pragma unroll
    for (int q = 0; q < 4; ++q) {
        int row = row0 + w * 16 + (l >> 4) * 4 + q;
        if (row >= NN) continue;
#pragma unroll
        for (int fj = 0; fj < 4; ++fj) {
            int j = jb + fj * 16;
            float rr = acc[fj][q];
            float zz = acc[4 + fj][q];
            float in_ = acc[8 + fj][q];
            float hn = acc[12 + fj][q];
            float r = 1.f / (1.f + __expf(-rr));
            float z = 1.f / (1.f + __expf(-zz));
            float n = tanhf(in_ + r * hn);
            float h = hin[(size_t)row * 64 + j];
            float val = (1.f - z) * n + z * h;
            fout[(size_t)row * 64 + j] = val;
            hfout[(size_t)row * 64 + j] = f2h(val);
        }
    }
}

extern "C" void kernel_launch(void* const* d_in, const int* in_sizes, int n_in,
                              void* d_out, int out_size, void* d_ws, size_t ws_size,
                              hipStream_t stream) {
    const float* hv0   = (const float*)d_in[0];
    const float* ef    = (const float*)d_in[1];
    const int*   src   = (const int*)d_in[2];
    const int*   dst   = (const int*)d_in[3];
    const float* W_msg = (const float*)d_in[4];
    const float* b_msg = (const float*)d_in[5];
    const float* W_ih  = (const float*)d_in[6];
    const float* W_hh  = (const float*)d_in[7];
    const float* b_ih  = (const float*)d_in[8];
    const float* b_hh  = (const float*)d_in[9];
    float* out = (float*)d_out;

    char* ws = (char*)d_ws;
    size_t off = 0;
    auto alloc = [&](size_t bytes) -> char* {
        char* p = ws + off;
        off = (off + bytes + 255) & ~(size_t)255;
        return p;
    };
    int*   cnt      = (int*)alloc((size_t)NC * NN * 4);
    int*   row_ptr  = (int*)alloc(NN * 4);
    int*   deg      = (int*)alloc(NN * 4);
    int*   cursor   = (int*)alloc((size_t)NC * NN * 4);
    int*   gcounter = (int*)alloc(4);
    int2*  adj      = (int2*)alloc((size_t)NE * 8);
    unsigned short* Ahi = (unsigned short*)alloc((size_t)MP * KA * 2);
    unsigned short* Alo = (unsigned short*)alloc((size_t)MP * KA * 2);
    unsigned short* Bhi = (unsigned short*)alloc((size_t)2 * 256 * KA * 2);
    unsigned short* Blo = (unsigned short*)alloc((size_t)2 * 256 * KA * 2);
    float* hv1      = (float*)alloc((size_t)NN * 64 * 4);
    unsigned short* hf0 = (unsigned short*)alloc((size_t)NN * 64 * 2);
    unsigned short* hf1 = (unsigned short*)alloc((size_t)NN * 64 * 2);

    // 5000 init blocks + 18 fold-main + 231 fold-aux
    prep_kernel<<<5000 + 18 + (2 * 29504 + 255) / 256, 256, 0, stream>>>(
        hv0, hf0, cnt, gcounter, W_msg, b_msg, W_ih, b_ih, b_hh, W_hh, Bhi, Blo);
    hist_kernel<<<(NE + 255) / 256, 256, 0, stream>>>(dst, cnt);
    scan_kernel<<<NB_SCAN, 256, 0, stream>>>(cnt, gcounter, row_ptr, deg, cursor);
    place_kernel<<<(NE + 255) / 256, 256, 0, stream>>>(src, dst, cursor, adj);

    // round 0 (gather also computes esum inline + writes A tail)
    gather_kernel<true><<<(NN + 3) / 4, 256, 0, stream>>>(
        hv0, hf0, row_ptr, deg, adj, ef, Ahi, Alo);
    gemm_gru<<<MP / 64, 256, 0, stream>>>(
        (const _Float16*)Ahi, (const _Float16*)Alo,
        (const _Float16*)Bhi, (const _Float16*)Blo,
        hv0, hv1, hf1);
    // round 1 (tail persists in Ahi)
    gather_kernel<false><<<(NN + 3) / 4, 256, 0, stream>>>(
        hv1, hf1, row_ptr, deg, adj, ef, Ahi, Alo);
    gemm_gru<<<MP / 64, 256, 0, stream>>>(
        (const _Float16*)Ahi, (const _Float16*)Alo,
        (const _Float16*)(Bhi + (size_t)256 * KA),
        (const _Float16*)(Blo + (size_t)256 * KA),
        hv1, out, hf1);
}